// Round 7
// baseline (261.046 us; speedup 1.0000x reference)
//
#include <hip/hip_runtime.h>
#include <hip/hip_bf16.h>

// ALiBi attention, B=8 L=1024 H=8 E=64, fp32 in/out, bf16 MFMA inside.
// Outputs: V [B,L,H,E] then series [B,H,L,L] concatenated in d_out.
// R7: key-split 8-wave blocks. Wave (qs,kh) = 16 q-rows x 512 keys.
// 512 thr/block, grid 1024 -> 32 waves/CU (2x R6). Swapped QK^T
// (mfma(K,Q)); PV via mfma_f32_16x16x16_bf16 (A-frag == QK D-frag, P
// register-resident). z and partial-O combined in-block via LDS
// (3 barriers total). P stored non-NT straight from D-frag.

typedef short short8 __attribute__((ext_vector_type(8)));
typedef short short4v __attribute__((ext_vector_type(4)));
typedef float f32x4 __attribute__((ext_vector_type(4)));
typedef unsigned short u16x4 __attribute__((ext_vector_type(4)));

#define B_ 8
#define L_ 1024
#define H_ 8
#define E_ 64
#define RSTRIDE (H_ * E_)  // 512 floats between seq rows of Q/K/V
#define QBLK 64            // q-rows per block (4 qs x 16)
#define NKT 32             // 16-key tiles per key-half

__device__ __forceinline__ unsigned short f2bf(float f) {
  return __builtin_bit_cast(unsigned short, __float2bfloat16(f));
}
__device__ __forceinline__ short8 ldfrag(const float* p) {
  float4 a = *reinterpret_cast<const float4*>(p);
  float4 b = *reinterpret_cast<const float4*>(p + 4);
  return (short8){(short)f2bf(a.x), (short)f2bf(a.y), (short)f2bf(a.z),
                  (short)f2bf(a.w), (short)f2bf(b.x), (short)f2bf(b.y),
                  (short)f2bf(b.z), (short)f2bf(b.w)};
}

__device__ __forceinline__ f32x4 mfma16(short4v a, short4v b, f32x4 c) {
#if __has_builtin(__builtin_amdgcn_mfma_f32_16x16x16bf16_1k)
  return __builtin_amdgcn_mfma_f32_16x16x16bf16_1k(a, b, c, 0, 0, 0);
#else
  asm volatile(
      "s_nop 1\n\t"
      "v_mfma_f32_16x16x16_bf16 %0, %1, %2, %0\n\t"
      "s_nop 2"
      : "+v"(c)
      : "v"(a), "v"(b));
  return c;
#endif
}

// ---- prep: Kbf[bh][s][e] bf16; VT[bh][e][s] bf16. grid 16*64, 256 thr ----
__global__ __launch_bounds__(256, 4) void prep_kv(
    const float* __restrict__ Kg, const float* __restrict__ Vg,
    unsigned short* __restrict__ Kbf, unsigned short* __restrict__ VTbf) {
  __shared__ unsigned short tile[64 * 64];  // V^T subtile [e][s], swizzled

  const int t = threadIdx.x;
  const int id = blockIdx.x;
  const int bh = id & 63;  // id%8 = h -> same XCD as main kernel's consumers
  const int sc = id >> 6;  // s-chunk 0..15
  const int h = bh & 7, b = bh >> 3;
  const int s0 = sc * 64;

  const float* Kb = Kg + ((size_t)b * L_ + s0) * RSTRIDE + h * E_;
  const float* Vb = Vg + ((size_t)b * L_ + s0) * RSTRIDE + h * E_;
  unsigned short* Ko = Kbf + ((size_t)bh * L_ + s0) * E_;
  unsigned short* Vo = VTbf + (size_t)bh * E_ * L_ + s0;  // row stride L_

  {  // K convert (coalesced both sides)
    const int e = 4 * (t & 15);
#pragma unroll
    for (int i = 0; i < 4; ++i) {
      const int s = (t >> 4) + 16 * i;
      float4 v = *reinterpret_cast<const float4*>(&Kb[(size_t)s * RSTRIDE + e]);
      *reinterpret_cast<u16x4*>(&Ko[s * 64 + e]) =
          (u16x4){f2bf(v.x), f2bf(v.y), f2bf(v.z), f2bf(v.w)};
    }
  }
  {  // V transpose into LDS (lane owns column e; coalesced reads)
    const int e = t & 63, w = t >> 6;
#pragma unroll
    for (int i = 0; i < 4; ++i) {
      const int s4 = 4 * w + 16 * i;
      const float* vp = &Vb[(size_t)s4 * RSTRIDE + e];
      u16x4 u = {f2bf(vp[0]), f2bf(vp[RSTRIDE]), f2bf(vp[2 * RSTRIDE]),
                 f2bf(vp[3 * RSTRIDE])};
      *reinterpret_cast<u16x4*>(
          &tile[e * 64 + (((s4 >> 3) ^ (e & 7)) << 3) + (s4 & 7)]) = u;
    }
  }
  __syncthreads();
  {  // write V^T rows (32B contiguous per thread)
    const int e = t >> 2;
    const int sb = 16 * (t & 3);
#pragma unroll
    for (int i = 0; i < 4; ++i) {
      const int sp = sb + 4 * i;
      u16x4 u = *reinterpret_cast<const u16x4*>(
          &tile[e * 64 + (((sp >> 3) ^ (e & 7)) << 3) + (sp & 7)]);
      *reinterpret_cast<u16x4*>(&Vo[(size_t)e * L_ + sp]) = u;
    }
  }
}

// ---- main: 8 waves, key-split, 3 barriers ----
__global__ __launch_bounds__(512, 8) void alibi_attn(
    const float* __restrict__ Qg, const unsigned short* __restrict__ Kbf,
    const unsigned short* __restrict__ VTbf, float* __restrict__ Vout,
    float* __restrict__ Pout) {
  __shared__ float zbuf[2][4][16];       // [kh][qs][q-col]
  __shared__ float obuf[4][16][65];      // [qs][4*et+r][lane], padded

  const int t = threadIdx.x;
  const int lane = t & 63;
  const int w = t >> 6;    // 0..7
  const int qs = w & 3;    // q-subtile
  const int kh = w >> 2;   // key half
  const int col = lane & 15;
  const int kg = lane >> 4;

  const int id = blockIdx.x;  // id%8 = h -> XCD-pinned K/VT in L2
  const int qb = id >> 6;
  const int bh = id & 63;
  const int h = bh & 7;
  const int b = bh >> 3;
  const int q0 = qb * QBLK;

  const float sc_l2e = 0.125f * 1.44269504f;
  const float sl_l2e = exp2f(-(float)(h + 1) * 0.125f) * 1.44269504f;

  const unsigned short* Kb = Kbf + (size_t)bh * (L_ * E_) +
                             (size_t)(512 * kh) * E_;  // this wave's key half
  const unsigned short* VTb = VTbf + (size_t)bh * (E_ * L_) + 512 * kh;

  // Q B-fragments: q-row = col, k = 8*kg + j (+32 for second slice)
  short8 qf0, qf1;
  {
    const float* qp =
        Qg + ((size_t)b * L_ + q0 + 16 * qs + col) * RSTRIDE + h * E_ + 8 * kg;
    qf0 = ldfrag(qp);
    qf1 = ldfrag(qp + 32);
  }

  // lane's key in tile kt: key = 512*kh + 16*kt + 4*kg + r
  const float kbias0 = sl_l2e * (float)(512 * kh + 4 * kg - 1023) - 32.0f;

  // ===== Pass A: z-half = sum over this wave's 512 keys =====
  float z0 = 0.f, z1 = 0.f, z2 = 0.f, z3 = 0.f;
#pragma unroll 4
  for (int kt = 0; kt < NKT; ++kt) {
    const unsigned short* kp = Kb + (16 * kt + col) * E_ + 8 * kg;
    short8 k0 = *reinterpret_cast<const short8*>(kp);
    short8 k1 = *reinterpret_cast<const short8*>(kp + 32);
    f32x4 acc = {0.f, 0.f, 0.f, 0.f};
    acc = __builtin_amdgcn_mfma_f32_16x16x32_bf16(k0, qf0, acc, 0, 0, 0);
    acc = __builtin_amdgcn_mfma_f32_16x16x32_bf16(k1, qf1, acc, 0, 0, 0);
    const float base = fmaf((float)(16 * kt), sl_l2e, kbias0);
    z0 += __builtin_amdgcn_exp2f(fmaf(acc[0], sc_l2e, base));
    z1 += __builtin_amdgcn_exp2f(fmaf(acc[1], sc_l2e, base + sl_l2e));
    z2 += __builtin_amdgcn_exp2f(fmaf(acc[2], sc_l2e, base + 2.f * sl_l2e));
    z3 += __builtin_amdgcn_exp2f(fmaf(acc[3], sc_l2e, base + 3.f * sl_l2e));
  }
  float z = (z0 + z1) + (z2 + z3);
  z += __shfl_xor(z, 16, 64);
  z += __shfl_xor(z, 32, 64);  // all lanes: z-half for q=col

  if (kg == 0) zbuf[kh][qs][col] = z;
  __syncthreads();
  const float minv = 1.0f / (zbuf[0][qs][col] + zbuf[1][qs][col]);

  // ===== Pass B: QK -> P (regs) -> {global store, PV via 16x16x16} =====
  f32x4 oacc[4];
#pragma unroll
  for (int et = 0; et < 4; ++et) oacc[et] = (f32x4){0.f, 0.f, 0.f, 0.f};

  float* Pb = Pout + ((size_t)(b * H_ + h) * L_ + q0 + 16 * qs) * L_ +
              (size_t)col * L_ + 512 * kh + 4 * kg;

#pragma unroll 2
  for (int kt = 0; kt < NKT; ++kt) {
    const unsigned short* kp = Kb + (16 * kt + col) * E_ + 8 * kg;
    short8 k0 = *reinterpret_cast<const short8*>(kp);
    short8 k1 = *reinterpret_cast<const short8*>(kp + 32);
    f32x4 acc = {0.f, 0.f, 0.f, 0.f};
    acc = __builtin_amdgcn_mfma_f32_16x16x32_bf16(k0, qf0, acc, 0, 0, 0);
    acc = __builtin_amdgcn_mfma_f32_16x16x32_bf16(k1, qf1, acc, 0, 0, 0);
    // V^T fragments for this 16-key tile (independent of acc)
    short4v vf[4];
#pragma unroll
    for (int et = 0; et < 4; ++et) {
      vf[et] = *reinterpret_cast<const short4v*>(
          &VTb[(size_t)(16 * et + col) * L_ + 16 * kt + 4 * kg]);
    }
    const float base = fmaf((float)(16 * kt), sl_l2e, kbias0);
    f32x4 pf;
    pf[0] = __builtin_amdgcn_exp2f(fmaf(acc[0], sc_l2e, base)) * minv;
    pf[1] = __builtin_amdgcn_exp2f(fmaf(acc[1], sc_l2e, base + sl_l2e)) * minv;
    pf[2] =
        __builtin_amdgcn_exp2f(fmaf(acc[2], sc_l2e, base + 2.f * sl_l2e)) * minv;
    pf[3] =
        __builtin_amdgcn_exp2f(fmaf(acc[3], sc_l2e, base + 3.f * sl_l2e)) * minv;
    // P store straight from D-frag (plain store: L2 merges 64B halves)
    *reinterpret_cast<f32x4*>(Pb + 16 * kt) = pf;
    // pack to bf16 A-frag (k = 4*kg + j == this lane's keys) and PV
    short4v pa = {(short)f2bf(pf[0]), (short)f2bf(pf[1]), (short)f2bf(pf[2]),
                  (short)f2bf(pf[3])};
#pragma unroll
    for (int et = 0; et < 4; ++et) oacc[et] = mfma16(pa, vf[et], oacc[et]);
  }

  // ===== in-block O combine: waves kh=1 push partials, kh=0 add+store ====
  if (kh == 1) {
#pragma unroll
    for (int et = 0; et < 4; ++et)
#pragma unroll
      for (int r = 0; r < 4; ++r) obuf[qs][4 * et + r][lane] = oacc[et][r];
  }
  __syncthreads();
  if (kh == 0) {
    float* Vo = Vout + (((size_t)b * L_ + q0 + 16 * qs) * H_ + h) * E_;
#pragma unroll
    for (int et = 0; et < 4; ++et) {
#pragma unroll
      for (int r = 0; r < 4; ++r) {
        const float o = oacc[et][r] + obuf[qs][4 * et + r][lane];
        __builtin_nontemporal_store(
            o, &Vo[(4 * kg + r) * RSTRIDE + 16 * et + col]);
      }
    }
  }
}

extern "C" void kernel_launch(void* const* d_in, const int* in_sizes, int n_in,
                              void* d_out, int out_size, void* d_ws,
                              size_t ws_size, hipStream_t stream) {
  const float* Q = (const float*)d_in[0];
  const float* K = (const float*)d_in[1];
  const float* V = (const float*)d_in[2];
  float* out = (float*)d_out;
  float* Vo = out;                              // [B,L,H,E]
  float* Po = out + (size_t)B_ * L_ * H_ * E_;  // [B,H,L,L]
  unsigned short* Kbf = (unsigned short*)d_ws;  // 8 MB
  unsigned short* VTbf = Kbf + (size_t)B_ * H_ * L_ * E_;  // 8 MB
  hipLaunchKernelGGL(prep_kv, dim3(16 * B_ * H_), dim3(256), 0, stream, K, V,
                     Kbf, VTbf);
  hipLaunchKernelGGL(alibi_attn, dim3((L_ / QBLK) * H_ * B_), dim3(512), 0,
                     stream, Q, Kbf, VTbf, Vo, Po);
}

// Round 8
// 95.583 us; speedup vs baseline: 2.7311x; 2.7311x over previous
//
#include <hip/hip_runtime.h>
#include <hip/hip_bf16.h>

// ALiBi attention, B=8 L=1024 H=8 E=64, fp32 in/out, bf16 MFMA inside.
// Outputs: V [B,L,H,E] then series [B,H,L,L] concatenated in d_out.
// R8: prep writes bf16 K and V^T chunks in GLOAD-LINEAR swizzled order.
// Main: per chunk, stage K/VT into LDS via global_load_lds(16B) shared by
// all 4 waves (kills the per-wave L2 request storm of R6/R7); fragments
// from LDS (XOR-swizzled, conflict-free); fixed-max softmax; P register-
// resident (QK D-frag == 16x16x16 A-frag); P stored from D-frag.

typedef short short8 __attribute__((ext_vector_type(8)));
typedef short short4v __attribute__((ext_vector_type(4)));
typedef float f32x4 __attribute__((ext_vector_type(4)));
typedef unsigned short u16x4 __attribute__((ext_vector_type(4)));

#define B_ 8
#define L_ 1024
#define H_ 8
#define E_ 64
#define RSTRIDE (H_ * E_)       // 512 floats between seq rows
#define QBLK 64                 // 4 waves x 16 q-rows
#define CHUNK 128               // keys per chunk
#define NCH (L_ / CHUNK)        // 8
#define CHUNK_USH (CHUNK * E_)  // 8192 ushorts = 16KB per chunk tile

__device__ __forceinline__ unsigned short f2bf(float f) {
  return __builtin_bit_cast(unsigned short, __float2bfloat16(f));
}
__device__ __forceinline__ short8 ldfrag(const float* p) {
  float4 a = *reinterpret_cast<const float4*>(p);
  float4 b = *reinterpret_cast<const float4*>(p + 4);
  return (short8){(short)f2bf(a.x), (short)f2bf(a.y), (short)f2bf(a.z),
                  (short)f2bf(a.w), (short)f2bf(b.x), (short)f2bf(b.y),
                  (short)f2bf(b.z), (short)f2bf(b.w)};
}

__device__ __forceinline__ f32x4 mfma16(short4v a, short4v b, f32x4 c) {
#if __has_builtin(__builtin_amdgcn_mfma_f32_16x16x16bf16_1k)
  return __builtin_amdgcn_mfma_f32_16x16x16bf16_1k(a, b, c, 0, 0, 0);
#else
  asm volatile(
      "s_nop 1\n\t"
      "v_mfma_f32_16x16x16_bf16 %0, %1, %2, %0\n\t"
      "s_nop 2"
      : "+v"(c)
      : "v"(a), "v"(b));
  return c;
#endif
}

// async 16B global->LDS; LDS dest = wave-uniform base + lane*16
__device__ __forceinline__ void gld16(const unsigned short* g,
                                      unsigned short* l) {
  __builtin_amdgcn_global_load_lds(
      (const __attribute__((address_space(1))) unsigned int*)g,
      (__attribute__((address_space(3))) unsigned int*)l, 16, 0, 0);
}

// ---- prep: scratch in gload-linear swizzled block order ----
// K chunk: 1024 16B-blocks; block j <-> (s = j>>3, e8 = (j&7)^(s&7)).
// VT chunk: block j <-> (e = j>>4, g = j&15; s-block g0 = g^(e&7)).
__global__ __launch_bounds__(256, 4) void prep_kv(
    const float* __restrict__ Kg, const float* __restrict__ Vg,
    unsigned short* __restrict__ Kbf, unsigned short* __restrict__ VTbf) {
  __shared__ unsigned short vt[64 * 128];  // V^T tile in swizzled space

  const int t = threadIdx.x;
  const int id = blockIdx.x;
  const int bh = id & 63;  // id%8 = h -> same XCD as consumers
  const int sc = id >> 6;  // chunk 0..7
  const int h = bh & 7, b = bh >> 3;
  const int s0 = sc * CHUNK;

  const float* Kb = Kg + ((size_t)b * L_ + s0) * RSTRIDE + h * E_;
  const float* Vb = Vg + ((size_t)b * L_ + s0) * RSTRIDE + h * E_;
  unsigned short* Ko = Kbf + (size_t)(bh * NCH + sc) * CHUNK_USH;
  unsigned short* Vo = VTbf + (size_t)(bh * NCH + sc) * CHUNK_USH;

  // K: direct convert into swizzled block order (reads stay coalesced)
#pragma unroll
  for (int i = 0; i < 4; ++i) {
    const int j = t + 256 * i;
    const int s = j >> 3;
    const int e8 = (j & 7) ^ (s & 7);
    const float* kp = Kb + (size_t)s * RSTRIDE + 8 * e8;
    float4 a = *reinterpret_cast<const float4*>(kp);
    float4 c = *reinterpret_cast<const float4*>(kp + 4);
    *reinterpret_cast<u16x4*>(&Ko[j * 8]) =
        (u16x4){f2bf(a.x), f2bf(a.y), f2bf(a.z), f2bf(a.w)};
    *reinterpret_cast<u16x4*>(&Ko[j * 8 + 4]) =
        (u16x4){f2bf(c.x), f2bf(c.y), f2bf(c.z), f2bf(c.w)};
  }
  // V: transpose through LDS (swizzled space), then linear copy out
  {
    const int e = t & 63, w = t >> 6;
#pragma unroll
    for (int i = 0; i < 8; ++i) {
      const int s4 = 4 * w + 16 * i;
      const float* vp = Vb + (size_t)s4 * RSTRIDE + e;
      u16x4 u = {f2bf(vp[0]), f2bf(vp[RSTRIDE]), f2bf(vp[2 * RSTRIDE]),
                 f2bf(vp[3 * RSTRIDE])};
      *reinterpret_cast<u16x4*>(
          &vt[e * 128 + (((s4 >> 3) ^ (e & 7)) << 3) + (s4 & 7)]) = u;
    }
  }
  __syncthreads();
#pragma unroll
  for (int i = 0; i < 4; ++i) {
    const int j = t + 256 * i;  // swizzled space is already block-linear
    u16x4 u0 = *reinterpret_cast<const u16x4*>(&vt[j * 8]);
    u16x4 u1 = *reinterpret_cast<const u16x4*>(&vt[j * 8 + 4]);
    *reinterpret_cast<u16x4*>(&Vo[j * 8]) = u0;
    *reinterpret_cast<u16x4*>(&Vo[j * 8 + 4]) = u1;
  }
}

// ---- main ----
__global__ __launch_bounds__(256, 4) void alibi_attn(
    const float* __restrict__ Qg, const unsigned short* __restrict__ Kbf,
    const unsigned short* __restrict__ VTbf, float* __restrict__ Vout,
    float* __restrict__ Pout) {
  __shared__ unsigned short sK[CHUNK_USH];   // 16KB, swizzled [s][e]
  __shared__ unsigned short sVT[CHUNK_USH];  // 16KB, swizzled [e][s]

  const int t = threadIdx.x;
  const int lane = t & 63;
  const int w = t >> 6;
  const int col = lane & 15;
  const int kg = lane >> 4;

  const int id = blockIdx.x;  // id%8 = h -> XCD-pinned scratch in L2
  const int qb = id >> 6;
  const int bh = id & 63;
  const int h = bh & 7;
  const int b = bh >> 3;
  const int q0 = qb * QBLK;

  const float sc_l2e = 0.125f * 1.44269504f;
  const float sl_l2e = exp2f(-(float)(h + 1) * 0.125f) * 1.44269504f;

  const unsigned short* Kc = Kbf + (size_t)bh * NCH * CHUNK_USH;
  const unsigned short* Vc = VTbf + (size_t)bh * NCH * CHUNK_USH;

  // Q B-fragments: q-row = col, k = 8*kg + j (+32 for second slice)
  short8 qf0, qf1;
  {
    const float* qp =
        Qg + ((size_t)b * L_ + q0 + 16 * w + col) * RSTRIDE + h * E_ + 8 * kg;
    qf0 = ldfrag(qp);
    qf1 = ldfrag(qp + 32);
  }

  // lane's key for D-frag row r: key = 128c + 16kt + 4kg + r
  const float kbias0 = sl_l2e * (float)(4 * kg - 1023) - 32.0f;

  // ===== Pass A: z = sum exp2(u-32) =====
  float z0 = 0.f, z1 = 0.f, z2 = 0.f, z3 = 0.f;
  for (int c = 0; c < NCH; ++c) {
    {  // stage K chunk: 16 x 1KB segments via global_load_lds
      const unsigned short* src = Kc + (size_t)c * CHUNK_USH;
#pragma unroll
      for (int i = 0; i < 4; ++i) {
        const int seg = i * 4 + w;
        gld16(src + (size_t)(seg * 64 + lane) * 8, &sK[seg * 512]);
      }
    }
    __syncthreads();
#pragma unroll 4
    for (int kt = 0; kt < 8; ++kt) {
      const int row = 16 * kt + col;
      short8 k0 = *reinterpret_cast<const short8*>(
          &sK[row * 64 + ((kg ^ (row & 7)) << 3)]);
      short8 k1 = *reinterpret_cast<const short8*>(
          &sK[row * 64 + (((kg + 4) ^ (row & 7)) << 3)]);
      f32x4 acc = {0.f, 0.f, 0.f, 0.f};
      acc = __builtin_amdgcn_mfma_f32_16x16x32_bf16(k0, qf0, acc, 0, 0, 0);
      acc = __builtin_amdgcn_mfma_f32_16x16x32_bf16(k1, qf1, acc, 0, 0, 0);
      const float base = fmaf((float)(128 * c + 16 * kt), sl_l2e, kbias0);
      z0 += __builtin_amdgcn_exp2f(fmaf(acc[0], sc_l2e, base));
      z1 += __builtin_amdgcn_exp2f(fmaf(acc[1], sc_l2e, base + sl_l2e));
      z2 += __builtin_amdgcn_exp2f(fmaf(acc[2], sc_l2e, base + 2.f * sl_l2e));
      z3 += __builtin_amdgcn_exp2f(fmaf(acc[3], sc_l2e, base + 3.f * sl_l2e));
    }
    __syncthreads();
  }
  float z = (z0 + z1) + (z2 + z3);
  z += __shfl_xor(z, 16, 64);
  z += __shfl_xor(z, 32, 64);
  const float minv = 1.0f / z;

  // ===== Pass B =====
  f32x4 oacc[4];
#pragma unroll
  for (int et = 0; et < 4; ++et) oacc[et] = (f32x4){0.f, 0.f, 0.f, 0.f};

  float* Pb = Pout + ((size_t)(b * H_ + h) * L_ + q0 + 16 * w + col) * L_ +
              4 * kg;

  for (int c = 0; c < NCH; ++c) {
    {  // stage K + VT chunks
      const unsigned short* srcK = Kc + (size_t)c * CHUNK_USH;
      const unsigned short* srcV = Vc + (size_t)c * CHUNK_USH;
#pragma unroll
      for (int i = 0; i < 4; ++i) {
        const int seg = i * 4 + w;
        gld16(srcK + (size_t)(seg * 64 + lane) * 8, &sK[seg * 512]);
        gld16(srcV + (size_t)(seg * 64 + lane) * 8, &sVT[seg * 512]);
      }
    }
    __syncthreads();
#pragma unroll 2
    for (int kt = 0; kt < 8; ++kt) {
      const int row = 16 * kt + col;
      short8 k0 = *reinterpret_cast<const short8*>(
          &sK[row * 64 + ((kg ^ (row & 7)) << 3)]);
      short8 k1 = *reinterpret_cast<const short8*>(
          &sK[row * 64 + (((kg + 4) ^ (row & 7)) << 3)]);
      f32x4 acc = {0.f, 0.f, 0.f, 0.f};
      acc = __builtin_amdgcn_mfma_f32_16x16x32_bf16(k0, qf0, acc, 0, 0, 0);
      acc = __builtin_amdgcn_mfma_f32_16x16x32_bf16(k1, qf1, acc, 0, 0, 0);
      // V^T fragments from LDS: e = 16et+col, s-block g0 = 2kt + (kg>>1)
      short4v vf[4];
      const int g0 = 2 * kt + (kg >> 1);
      const int so = 4 * (kg & 1);
#pragma unroll
      for (int et = 0; et < 4; ++et) {
        const int e = 16 * et + col;
        vf[et] = *reinterpret_cast<const short4v*>(
            &sVT[e * 128 + ((g0 ^ (e & 7)) << 3) + so]);
      }
      const float base = fmaf((float)(128 * c + 16 * kt), sl_l2e, kbias0);
      f32x4 pf;
      pf[0] = __builtin_amdgcn_exp2f(fmaf(acc[0], sc_l2e, base)) * minv;
      pf[1] =
          __builtin_amdgcn_exp2f(fmaf(acc[1], sc_l2e, base + sl_l2e)) * minv;
      pf[2] = __builtin_amdgcn_exp2f(fmaf(acc[2], sc_l2e, base + 2.f * sl_l2e)) *
              minv;
      pf[3] = __builtin_amdgcn_exp2f(fmaf(acc[3], sc_l2e, base + 3.f * sl_l2e)) *
              minv;
      // P store straight from D-frag (16 rows x 64B per instruction)
      *reinterpret_cast<f32x4*>(Pb + 128 * c + 16 * kt) = pf;
      // pack to bf16 A-frag (k = 4*kg + j == this lane's keys) and PV
      short4v pa = {(short)f2bf(pf[0]), (short)f2bf(pf[1]), (short)f2bf(pf[2]),
                    (short)f2bf(pf[3])};
#pragma unroll
      for (int et = 0; et < 4; ++et) oacc[et] = mfma16(pa, vf[et], oacc[et]);
    }
    __syncthreads();
  }

  // ---- write O: q = q0+16w+4kg+r, e = 16et+col ----
  float* Vo = Vout + (((size_t)b * L_ + q0 + 16 * w) * H_ + h) * E_;
#pragma unroll
  for (int et = 0; et < 4; ++et) {
#pragma unroll
    for (int r = 0; r < 4; ++r) {
      __builtin_nontemporal_store(oacc[et][r],
                                  &Vo[(4 * kg + r) * RSTRIDE + 16 * et + col]);
    }
  }
}

extern "C" void kernel_launch(void* const* d_in, const int* in_sizes, int n_in,
                              void* d_out, int out_size, void* d_ws,
                              size_t ws_size, hipStream_t stream) {
  const float* Q = (const float*)d_in[0];
  const float* K = (const float*)d_in[1];
  const float* V = (const float*)d_in[2];
  float* out = (float*)d_out;
  float* Vo = out;                              // [B,L,H,E]
  float* Po = out + (size_t)B_ * L_ * H_ * E_;  // [B,H,L,L]
  unsigned short* Kbf = (unsigned short*)d_ws;  // 8 MB
  unsigned short* VTbf = Kbf + (size_t)B_ * H_ * L_ * E_;  // 8 MB
  hipLaunchKernelGGL(prep_kv, dim3(NCH * B_ * H_), dim3(256), 0, stream, K, V,
                     Kbf, VTbf);
  hipLaunchKernelGGL(alibi_attn, dim3((L_ / QBLK) * H_ * B_), dim3(256), 0,
                     stream, Q, Kbf, VTbf, Vo, Po);
}